// Round 8
// baseline (517.639 us; speedup 1.0000x reference)
//
#include <hip/hip_runtime.h>

// ---------------------------------------------------------------------------
// GNNQNetwork hetero-GAT, MI355X fp32. Round 12.
//
// R12 = R11 with precompute folded into prep (5 -> 4 kernels). Measured
// inter-dispatch overhead ~35-45us/boundary (kernel-sum ~310us vs 504 total);
// edge kernels are at their request-count minimum, so the cheapest win is one
// fewer boundary:
//   - prepF blocks 0..5: Cws materialization + P4 zero (old precompute).
//   - prepF blocks 6..592: redundantly compute vs/vd = enc.(W@a) per block
//     (right-assoc form, numerics validated in R8), then process ~4 nodes
//     per thread (587 blocks so the W re-read broadcast is only ~225MB L2,
//     ~8us). Node body identical to R11's prep.
//   - edgeA / edgeB / tail: byte-identical to R11 (proven 137/~130/~30us).
// ---------------------------------------------------------------------------

constexpr int kNT = 100000, kNRV = 200000, kNR = 300000, kE = 400000;
constexpr int kNN = kNT + kNRV + kNR;   // 600000 nodes
constexpr int kSLOT = 1088;        // per-et P tile: 16x64 acc + 64 cnt
constexpr int kPSZ  = 6 * kSLOT;   // 6528
constexpr int kNBE  = 342;         // blocks per edge type
constexpr int kNTH  = kNBE * 256;  // 87552 threads per edge type
constexpr int kEPT  = 5;           // edge slots per thread (5*87552 >= 400k)
constexpr int kPNB  = 587;         // prepF node blocks (4 nodes/thread)

// workspace offsets in 4-byte units (total 34.56 MB <= 34.61 proven)
constexpr long long OFF_C    = 0;        // 6*2176 C rows + bias@2048
constexpr long long OFF_P4   = 13296;    // 4 staged P copies: 4*6528 = 26112
constexpr long long OFF_LS6  = 39408;    // dense src logits, 1.2M
constexpr long long OFF_LD6  = 1239408;  // dense dst logits, 1.2M
constexpr long long OFF_W16  = 2439408;  // 2.4M halves = 1.2M floats
constexpr long long OFF_DEN  = 3639408;  // {den,batch} float2 x 1.2M = 2.4M
constexpr long long OFF_SRV  = 6039408;  // rv recs: 200k*8 floats (32B)
constexpr long long OFF_ST   = 7639408;  // t recs: 100k*4 floats (16B)
constexpr long long OFF_SR   = 8039408;  // r recs: 300k*2 floats (8B)
// end 8639408 floats = 34.558 MB

// per-et tables. src type: rv,t,r,rv,t,r ; dst type: t,rv,rv,r,r,t
__constant__ const int kDRB[6]  = {0, 100000, 300000, 500000, 800000, 1100000};
__constant__ const int kDLEN[6] = {100000, 200000, 200000, 300000, 300000, 100000};
__constant__ const int kLSB6[6] = {0, 400000, 600000, 200000, 500000, 900000};

// ---------------------------------------------------------------------------
__device__ __forceinline__ int lowb(const int* a, int n, int v) {
  int lo = 0, hi = n;
  while (lo < hi) { int mid = (lo + hi) >> 1; if (a[mid] < v) lo = mid + 1; else hi = mid; }
  return lo;
}

static __device__ __forceinline__ unsigned p2h(float a, float b) {
  _Float16 ha = (_Float16)a, hb = (_Float16)b;
  unsigned short ua = __builtin_bit_cast(unsigned short, ha);
  unsigned short ub = __builtin_bit_cast(unsigned short, hb);
  return (unsigned)ua | ((unsigned)ub << 16);
}

// ---------------------------------------------------------------------------
// prepF: blocks 0..5 = Cws + P4 zero; blocks 6.. = redundant vs/vd + node prep
__global__ __launch_bounds__(256) void prepF_kernel(
    const float* __restrict__ x_t, const float* __restrict__ x_rv,
    const float* __restrict__ x_r,
    const int* __restrict__ bt, const int* __restrict__ brv,
    const int* __restrict__ br,
    const float* encW_t, const float* encb_t,
    const float* encW_rv, const float* encb_rv,
    const float* encW_r, const float* encb_r,
    const float* W0, const float* as0, const float* ad0,
    const float* W1, const float* as1, const float* ad1,
    const float* W2, const float* as2, const float* ad2,
    const float* W3, const float* as3, const float* ad3,
    const float* W4, const float* as4, const float* ad4,
    const float* W5, const float* as5, const float* ad5,
    uint4* __restrict__ SRVq, uint4* __restrict__ STq, uint2* __restrict__ SRq,
    float* __restrict__ LS6, float* __restrict__ LD6,
    float2* __restrict__ DEN,
    float* __restrict__ Cws, float* __restrict__ P4)
{
  const float* encW[3] = {encW_t, encW_rv, encW_r};
  const float* encb[3] = {encb_t, encb_rv, encb_r};
  const int    Ks[3]   = {8, 13, 4};
  const float* Wv[6]  = {W0, W1, W2, W3, W4, W5};
  const float* asv[6] = {as0, as1, as2, as3, as4, as5};
  const float* adv[6] = {ad0, ad1, ad2, ad3, ad4, ad5};
  const int srcT[6] = {1, 0, 2, 1, 0, 2};
  const int dstT[6] = {0, 1, 1, 2, 2, 0};
  int tid = threadIdx.x;

  if (blockIdx.x < 6) {
    // ---- old precompute: Cws slab + P4 zero ----
    int et = blockIdx.x;
    for (int i = et * 256 + tid; i < 4 * kPSZ; i += 6 * 256) P4[i] = 0.f;
    int st = srcT[et];
    int K = Ks[st];
    const float* eW = encW[st];
    const float* eB = encb[st];
    const float* W = Wv[et];
    float* Cslot = Cws + et * 2176;
    for (int idx = tid; idx < (K + 1) * 128; idx += 256) {
      int r = idx >> 7, j = idx & 127;
      const float* row = (r < K) ? (eW + r * 128) : eB;
      float acc = 0.f;
      for (int m = 0; m < 128; ++m) acc += row[m] * W[m * 128 + j];
      Cslot[(r < K) ? (r * 128 + j) : (2048 + j)] = acc;
    }
    return;
  }

  // ---- redundant per-block vs/vd = enc . (W @ a) (right-assoc, R8-proven) ----
  __shared__ float wsS[6][128], wdS[6][128];
  __shared__ float vsL[6][20], vdL[6][20];
  if (tid < 128) {
    for (int et = 0; et < 6; ++et) {
      const float* row = Wv[et] + tid * 128;
      const float* aS = asv[et];
      const float* aD = adv[et];
      float accS = 0.f, accD = 0.f;
      for (int j = 0; j < 128; ++j) {
        float w = row[j];
        accS += w * aS[j];
        accD += w * aD[j];
      }
      wsS[et][tid] = accS;
      wdS[et][tid] = accD;
    }
  }
  __syncthreads();
  if (tid < 192) {
    int et = tid >> 5, k = tid & 31;
    int st = srcT[et], K = Ks[st];
    if (k <= K) {
      const float* row = (k < K) ? (encW[st] + k * 128) : encb[st];
      float acc = 0.f;
      for (int m = 0; m < 128; ++m) acc += row[m] * wsS[et][m];
      vsL[et][k < K ? k : 16] = acc;
    }
    int dt = dstT[et], KD = Ks[dt];
    if (k <= KD) {
      const float* row = (k < KD) ? (encW[dt] + k * 128) : encb[dt];
      float acc = 0.f;
      for (int m = 0; m < 128; ++m) acc += row[m] * wdS[et][m];
      vdL[et][k < KD ? k : 16] = acc;
    }
  }
  __syncthreads();

  // ---- node prep, ~4 nodes/thread (grid-stride over 587 node blocks) ----
  for (int n = (blockIdx.x - 6) * 256 + tid; n < kNN; n += kPNB * 256) {
    if (n < kNT) {
      // tile: src roles et1,et4 (K=8); dst roles et0,et5
      const float* xr = x_t + n * 8;
      float bf = (float)bt[n];
      const float* vsA = &vsL[1][0], *vsB = &vsL[4][0];
      const float* vdA = &vdL[0][0], *vdB = &vdL[5][0];
      float x[8]; float a0 = 0, a1 = 0, a2 = 0, a3 = 0;
#pragma unroll
      for (int k = 0; k < 8; ++k) {
        x[k] = xr[k];
        a0 += x[k] * vsA[k]; a1 += x[k] * vsB[k];
        a2 += x[k] * vdA[k]; a3 += x[k] * vdB[k];
      }
      STq[n] = make_uint4(p2h(x[0], x[1]), p2h(x[2], x[3]),
                          p2h(x[4], x[5]), p2h(x[6], x[7]));
      LS6[400000 + n] = a0 + vsA[16];
      LS6[500000 + n] = a1 + vsB[16];
      LD6[n] = a2 + vdA[16];
      LD6[1100000 + n] = a3 + vdB[16];
      DEN[n] = make_float2(0.f, bf);
      DEN[1100000 + n] = make_float2(0.f, bf);
    } else if (n < kNT + kNRV) {
      int m = n - kNT;
      // rv: src roles et0,et3 (K=13); dst roles et1,et2
      const float* xr = x_rv + m * 13;
      float bf = (float)brv[m];
      const float* vsA = &vsL[0][0], *vsB = &vsL[3][0];
      const float* vdA = &vdL[1][0], *vdB = &vdL[2][0];
      float x[13]; float a0 = 0, a1 = 0, a2 = 0, a3 = 0;
#pragma unroll
      for (int k = 0; k < 13; ++k) {
        x[k] = xr[k];
        a0 += x[k] * vsA[k]; a1 += x[k] * vsB[k];
        a2 += x[k] * vdA[k]; a3 += x[k] * vdB[k];
      }
      SRVq[(long long)m * 2] =
          make_uint4(p2h(x[0], x[1]), p2h(x[2], x[3]), p2h(x[4], x[5]), p2h(x[6], x[7]));
      SRVq[(long long)m * 2 + 1] =
          make_uint4(p2h(x[8], x[9]), p2h(x[10], x[11]), p2h(x[12], 0.f), 0);
      LS6[m] = a0 + vsA[16];
      LS6[200000 + m] = a1 + vsB[16];
      LD6[100000 + m] = a2 + vdA[16];
      LD6[300000 + m] = a3 + vdB[16];
      DEN[100000 + m] = make_float2(0.f, bf);
      DEN[300000 + m] = make_float2(0.f, bf);
    } else {
      int m = n - kNT - kNRV;
      // road: src roles et2,et5 (K=4); dst roles et3,et4
      const float* xr = x_r + m * 4;
      float bf = (float)br[m];
      const float* vsA = &vsL[2][0], *vsB = &vsL[5][0];
      const float* vdA = &vdL[3][0], *vdB = &vdL[4][0];
      float x[4]; float a0 = 0, a1 = 0, a2 = 0, a3 = 0;
#pragma unroll
      for (int k = 0; k < 4; ++k) {
        x[k] = xr[k];
        a0 += x[k] * vsA[k]; a1 += x[k] * vsB[k];
        a2 += x[k] * vdA[k]; a3 += x[k] * vdB[k];
      }
      SRq[m] = make_uint2(p2h(x[0], x[1]), p2h(x[2], x[3]));
      LS6[600000 + m] = a0 + vsA[16];
      LS6[900000 + m] = a1 + vsB[16];
      LD6[500000 + m] = a2 + vdA[16];
      LD6[800000 + m] = a3 + vdB[16];
      DEN[500000 + m] = make_float2(0.f, bf);
      DEN[800000 + m] = make_float2(0.f, bf);
    }
  }
}

// ---------------------------------------------------------------------------
__device__ __forceinline__ void pickSD(
    int et,
    const int* s0, const int* s1, const int* s2,
    const int* s3, const int* s4, const int* s5,
    const int* d0, const int* d1, const int* d2,
    const int* d3, const int* d4, const int* d5,
    const int*& sp, const int*& dp)
{
  switch (et) {
    case 0: sp = s0; dp = d0; break;
    case 1: sp = s1; dp = d1; break;
    case 2: sp = s2; dp = d2; break;
    case 3: sp = s3; dp = d3; break;
    case 4: sp = s4; dp = d4; break;
    default: sp = s5; dp = d5; break;
  }
}

// ---------------------------------------------------------------------------
// edgeA: w = exp(leaky(ls+ld)); W16[i] = w (streamed); DEN.x += w (atomic).
// Read-only gathers (LS6, LD6) fully separated from the atomic region (DEN).
__global__ __launch_bounds__(256, 8) void edgeA_kernel(
    const int* s0, const int* s1, const int* s2,
    const int* s3, const int* s4, const int* s5,
    const int* d0, const int* d1, const int* d2,
    const int* d3, const int* d4, const int* d5,
    const float* __restrict__ LS6, const float* __restrict__ LD6,
    _Float16* __restrict__ W16, float* __restrict__ DENf)
{
  int et = blockIdx.x / kNBE;
  int bIdx = blockIdx.x - et * kNBE;
  const int* sp; const int* dp;
  pickSD(et, s0, s1, s2, s3, s4, s5, d0, d1, d2, d3, d4, d5, sp, dp);
  const float* Lsrc = LS6 + kLSB6[et];
  const float* Ldst = LD6 + kDRB[et];
  const int drb = kDRB[et];
  _Float16* Wet = W16 + (long long)et * kE;
  int base = bIdx * 256 + (int)threadIdx.x;

  int s[kEPT], d[kEPT]; bool ok[kEPT];
#pragma unroll
  for (int j = 0; j < kEPT; ++j) {
    int e = base + j * kNTH;
    ok[j] = e < kE;
    int ee = ok[j] ? e : 0;
    s[j] = sp[ee]; d[j] = dp[ee];
  }
  float ls[kEPT];
#pragma unroll
  for (int j = 0; j < kEPT; ++j) ls[j] = Lsrc[s[j]];
  float ld[kEPT];
#pragma unroll
  for (int j = 0; j < kEPT; ++j) ld[j] = Ldst[d[j]];
#pragma unroll
  for (int j = 0; j < kEPT; ++j) {
    float t = ls[j] + ld[j];
    t = t > 0.f ? t : 0.2f * t;
    float w = __expf(t);
    if (ok[j]) {
      Wet[base + j * kNTH] = (_Float16)w;
      unsafeAtomicAdd(&DENf[(long long)(drb + d[j]) * 2], w);
    }
  }
}

// ---------------------------------------------------------------------------
// edgeB: streamed W16 read + DEN {den,batch} gather + x-rec gather;
// alpha*x into LDS [k][64 batches]; cnt sweep; dump to P4.
template <int TYPE>
__device__ __forceinline__ void ebflow(
    int bIdx,
    const int* __restrict__ sp, const int* __restrict__ dp,
    const uint4* __restrict__ srq4, const uint2* __restrict__ srq2,
    const _Float16* __restrict__ Wet, const float2* __restrict__ DEN2,
    int drb, int dlen, float* lp)
{
  constexpr int K = (TYPE == 0) ? 8 : ((TYPE == 1) ? 13 : 4);
  const int tid = threadIdx.x;
  const int lane = tid & 63;
  int base = bIdx * 256 + tid;

  int s[kEPT], d[kEPT]; bool ok[kEPT];
#pragma unroll
  for (int j = 0; j < kEPT; ++j) {
    int e = base + j * kNTH;
    ok[j] = e < kE;
    int ee = ok[j] ? e : 0;
    s[j] = sp[ee]; d[j] = dp[ee];
  }
  float w[kEPT];
#pragma unroll
  for (int j = 0; j < kEPT; ++j) {
    int e = base + j * kNTH;
    w[j] = (float)Wet[ok[j] ? e : 0];
  }
  uint4 q0[kEPT], q1[kEPT]; uint2 r2v[kEPT];
#pragma unroll
  for (int j = 0; j < kEPT; ++j) {
    if (TYPE == 0) {
      q0[j] = srq4[s[j]];
    } else if (TYPE == 1) {
      q0[j] = srq4[(long long)s[j] * 2];
      q1[j] = srq4[(long long)s[j] * 2 + 1];
    } else {
      r2v[j] = srq2[s[j]];
    }
  }
  float2 f2[kEPT];
#pragma unroll
  for (int j = 0; j < kEPT; ++j) f2[j] = DEN2[drb + d[j]];

#pragma unroll
  for (int j = 0; j < kEPT; ++j) {
    if (!ok[j]) continue;
    int b = (int)f2[j].y;
    float alpha = w[j] / fmaxf(f2[j].x, 1e-16f);
    float xv[K];
    if (TYPE == 0) {
      const _Float16* h = (const _Float16*)&q0[j];
#pragma unroll
      for (int k = 0; k < 8; ++k) xv[k] = (float)h[k];
    } else if (TYPE == 1) {
      const _Float16* h = (const _Float16*)&q0[j];
#pragma unroll
      for (int k = 0; k < 8; ++k) xv[k] = (float)h[k];
      const _Float16* h2 = (const _Float16*)&q1[j];
#pragma unroll
      for (int k = 0; k < 5; ++k) xv[8 + k] = (float)h2[k];
    } else {
      const _Float16* h = (const _Float16*)&r2v[j];
#pragma unroll
      for (int k = 0; k < 4; ++k) xv[k] = (float)h[k];
    }
#pragma unroll
    for (int k = 0; k < K; ++k) atomicAdd(lp + k * 64 + b, alpha * xv[k]);
  }

  // cnt: dense sweep of DEN {den,batch}; wave-segmented scan, one LDS
  // atomic per batch run (batch ids sorted by node index).
  for (int base2 = bIdx * 256 + (tid & ~63); base2 < dlen; base2 += kNTH) {
    int j2 = base2 + lane;
    bool a2 = j2 < dlen;
    float2 r2 = a2 ? DEN2[drb + j2] : make_float2(0.f, 0.f);
    int b2 = a2 ? (int)r2.y : (64 + lane);
    int v = (a2 && r2.x > 0.f) ? 1 : 0;
#pragma unroll
    for (int d2 = 1; d2 < 64; d2 <<= 1) {
      int ob = __shfl_up(b2, d2);
      int ov = __shfl_up(v, d2);
      if (lane >= d2 && ob == b2) v += ov;
    }
    int bn = __shfl_down(b2, 1);
    if (((lane == 63) || (bn != b2)) && v > 0) atomicAdd(lp + 1024 + b2, (float)v);
  }
}

__global__ __launch_bounds__(256, 4) void edgeB_kernel(
    const int* s0, const int* s1, const int* s2,
    const int* s3, const int* s4, const int* s5,
    const int* d0, const int* d1, const int* d2,
    const int* d3, const int* d4, const int* d5,
    const uint4* SRVq, const uint4* STq, const uint2* SRq,
    const _Float16* __restrict__ W16, const float2* __restrict__ DEN2,
    float* __restrict__ P4)
{
  __shared__ float lp[kSLOT];
  for (int j = threadIdx.x; j < kSLOT; j += 256) lp[j] = 0.f;
  __syncthreads();
  int et = blockIdx.x / kNBE;
  int bIdx = blockIdx.x - et * kNBE;
  const _Float16* Wet = W16 + (long long)et * kE;
  constexpr int KK[6] = {13, 8, 4, 13, 8, 4};
  switch (et) {
    case 0: ebflow<1>(bIdx, s0, d0, SRVq, nullptr, Wet, DEN2, 0,       100000, lp); break;
    case 1: ebflow<0>(bIdx, s1, d1, STq,  nullptr, Wet, DEN2, 100000,  200000, lp); break;
    case 2: ebflow<2>(bIdx, s2, d2, nullptr, SRq,  Wet, DEN2, 300000,  200000, lp); break;
    case 3: ebflow<1>(bIdx, s3, d3, SRVq, nullptr, Wet, DEN2, 500000,  300000, lp); break;
    case 4: ebflow<0>(bIdx, s4, d4, STq,  nullptr, Wet, DEN2, 800000,  300000, lp); break;
    default: ebflow<2>(bIdx, s5, d5, nullptr, SRq, Wet, DEN2, 1100000, 100000, lp); break;
  }
  __syncthreads();
  int K = KK[et];
  float* slab = P4 + (long long)(blockIdx.x & 3) * kPSZ + (long long)et * kSLOT;
  for (int i = threadIdx.x; i < kSLOT; i += 256) {
    if (i >= K * 64 && i < 1024) continue;
    float v = lp[i];
    if (v != 0.f) unsafeAtomicAdd(&slab[i], v);
  }
}

// ---------------------------------------------------------------------------
// tail: grid 64 graphs x 8 column-groups. Each block redundantly builds
// xrow for its graph, then computes 64 output columns (two half-K slices).
__global__ __launch_bounds__(128) void tail_kernel(
    const int* __restrict__ bt, const int* __restrict__ brv, const int* __restrict__ br,
    const float* __restrict__ xp,
    const float* __restrict__ fc1W, const float* __restrict__ fc1b,
    const float* __restrict__ fc2W, const float* __restrict__ fc2b,
    const float* __restrict__ outW, const float* __restrict__ outb,
    const float* __restrict__ b_rv2t, const float* __restrict__ b_r2t,
    const float* __restrict__ b_t2rv, const float* __restrict__ b_r2rv,
    const float* __restrict__ b_rv2r, const float* __restrict__ b_t2r,
    const float* __restrict__ Cws, const float* __restrict__ P4,
    float* __restrict__ out)
{
  int b = blockIdx.x >> 3;
  int half = blockIdx.x & 7;
  int tid = threadIdx.x;
  __shared__ float xrow[512];
  __shared__ float p1s[128];
  __shared__ float xps[64];
  __shared__ float psA[15], psB[15];
  __shared__ float part[128];
  __shared__ int cnts[3];

  if (tid < 64) xps[tid] = xp[b * 64 + tid];
  if (tid >= 64 && tid < 67) {
    int t = tid - 64;
    const int* ba = (t == 0) ? bt : (t == 1 ? brv : br);
    int N = (t == 0) ? kNT : (t == 1 ? kNRV : kNR);
    cnts[t] = lowb(ba, N, b + 1) - lowb(ba, N, b);
  }
  __syncthreads();

  // player branch
  float a = fc1b[tid];
  for (int k = 0; k < 64; ++k) a += xps[k] * fc1W[k * 128 + tid];
  p1s[tid] = fmaxf(a, 0.f);
  __syncthreads();
  float a2 = fc2b[tid];
  for (int k = 0; k < 128; ++k) a2 += p1s[k] * fc2W[k * 128 + tid];
  xrow[384 + tid] = fmaxf(a2, 0.f);

  const int etA[3] = {0, 1, 3}, etB[3] = {5, 2, 4};
  const int KAv[3] = {13, 8, 13}, KBv[3] = {4, 4, 8};
  for (int t3 = 0; t3 < 3; ++t3) {
    __syncthreads();
    int eA = etA[t3], eB = etB[t3];
    if (tid < 15) {
      int idx = (tid < 14) ? (tid * 64 + b) : (1024 + b);
      float sum = 0.f;
#pragma unroll
      for (int c = 0; c < 4; ++c) sum += P4[c * kPSZ + eA * kSLOT + idx];
      psA[tid] = sum;
    } else if (tid < 30) {
      int t = tid - 15;
      int idx = (t < 14) ? (t * 64 + b) : (1024 + b);
      float sum = 0.f;
#pragma unroll
      for (int c = 0; c < 4; ++c) sum += P4[c * kPSZ + eB * kSLOT + idx];
      psB[t] = sum;
    }
    __syncthreads();
    int KA = KAv[t3], KB = KBv[t3];
    const float* CA = Cws + eA * 2176;
    const float* CB = Cws + eB * 2176;
    float v = psA[14] * CA[2048 + tid] + psB[14] * CB[2048 + tid];
    for (int k = 0; k < KA; ++k) v += psA[k] * CA[k * 128 + tid];
    for (int k = 0; k < KB; ++k) v += psB[k] * CB[k * 128 + tid];
    float cnt = (float)max(cnts[t3], 1);
    const float* bb1 = (t3 == 0) ? b_rv2t : (t3 == 1 ? b_t2rv : b_rv2r);
    const float* bb2 = (t3 == 0) ? b_r2t  : (t3 == 1 ? b_r2rv : b_t2r);
    xrow[t3 * 128 + tid] = v / cnt + bb1[tid] + bb2[tid];
  }
  __syncthreads();

  // output GEMV slice: 64 columns c = half*64 + (tid&63); k-half per tid>>6
  {
    int c = half * 64 + (tid & 63);
    int kh = tid >> 6;                       // 0 or 1
    const float* Wc = outW + c;
    float acc = 0.f;
    int k0 = kh * 256;
#pragma unroll 8
    for (int k = k0; k < k0 + 256; ++k) acc += xrow[k] * Wc[(long long)k * 512];
    part[tid] = acc;
    __syncthreads();
    if (tid < 64) out[b * 512 + c] = outb[c] + part[tid] + part[tid + 64];
  }
}

// ---------------------------------------------------------------------------
extern "C" void kernel_launch(void* const* d_in, const int* in_sizes, int n_in,
                              void* d_out, int out_size, void* d_ws, size_t ws_size,
                              hipStream_t stream) {
  const float* x_tile   = (const float*)d_in[0];
  const float* x_rv     = (const float*)d_in[1];
  const float* x_road   = (const float*)d_in[2];
  const float* x_player = (const float*)d_in[3];
  const float* enc_t_W  = (const float*)d_in[4];
  const float* enc_t_b  = (const float*)d_in[5];
  const float* enc_rv_W = (const float*)d_in[6];
  const float* enc_rv_b = (const float*)d_in[7];
  const float* enc_r_W  = (const float*)d_in[8];
  const float* enc_r_b  = (const float*)d_in[9];
  const float* W[6]; const float* As[6]; const float* Ad[6]; const float* Bb[6];
  for (int et = 0; et < 6; ++et) {
    W[et]  = (const float*)d_in[10 + 4 * et];
    As[et] = (const float*)d_in[11 + 4 * et];
    Ad[et] = (const float*)d_in[12 + 4 * et];
    Bb[et] = (const float*)d_in[13 + 4 * et];
  }
  const float* fc1W = (const float*)d_in[34];
  const float* fc1b = (const float*)d_in[35];
  const float* fc2W = (const float*)d_in[36];
  const float* fc2b = (const float*)d_in[37];
  const float* outW = (const float*)d_in[38];
  const float* outb = (const float*)d_in[39];
  const int* esrc[6]; const int* edst[6];
  for (int et = 0; et < 6; ++et) {
    esrc[et] = (const int*)d_in[40 + 2 * et];
    edst[et] = (const int*)d_in[41 + 2 * et];
  }
  const int* batch_t  = (const int*)d_in[52];
  const int* batch_rv = (const int*)d_in[53];
  const int* batch_r  = (const int*)d_in[54];

  float* wsF = (float*)d_ws;
  float* Cws  = wsF + OFF_C;
  float* P4   = wsF + OFF_P4;
  float* LS6  = wsF + OFF_LS6;
  float* LD6  = wsF + OFF_LD6;
  _Float16* W16 = (_Float16*)(wsF + OFF_W16);
  float* DENf = wsF + OFF_DEN;
  float2* DEN2 = (float2*)(wsF + OFF_DEN);
  uint4* SRVq = (uint4*)(wsF + OFF_SRV);
  uint4* STq  = (uint4*)(wsF + OFF_ST);
  uint2* SRq  = (uint2*)(wsF + OFF_SR);
  float* out  = (float*)d_out;

  prepF_kernel<<<6 + kPNB, 256, 0, stream>>>(
      x_tile, x_rv, x_road, batch_t, batch_rv, batch_r,
      enc_t_W, enc_t_b, enc_rv_W, enc_rv_b, enc_r_W, enc_r_b,
      W[0], As[0], Ad[0], W[1], As[1], Ad[1], W[2], As[2], Ad[2],
      W[3], As[3], Ad[3], W[4], As[4], Ad[4], W[5], As[5], Ad[5],
      SRVq, STq, SRq, LS6, LD6, DEN2, Cws, P4);

  edgeA_kernel<<<6 * kNBE, 256, 0, stream>>>(
      esrc[0], esrc[1], esrc[2], esrc[3], esrc[4], esrc[5],
      edst[0], edst[1], edst[2], edst[3], edst[4], edst[5],
      LS6, LD6, W16, DENf);

  edgeB_kernel<<<6 * kNBE, 256, 0, stream>>>(
      esrc[0], esrc[1], esrc[2], esrc[3], esrc[4], esrc[5],
      edst[0], edst[1], edst[2], edst[3], edst[4], edst[5],
      SRVq, STq, SRq, W16, DEN2, P4);

  tail_kernel<<<64 * 8, 128, 0, stream>>>(
      batch_t, batch_rv, batch_r, x_player,
      fc1W, fc1b, fc2W, fc2b, outW, outb,
      Bb[0], Bb[5], Bb[1], Bb[2], Bb[3], Bb[4],
      Cws, P4, out);

  (void)in_sizes; (void)n_in; (void)out_size; (void)ws_size;
}

// Round 9
// 501.201 us; speedup vs baseline: 1.0328x; 1.0328x over previous
//
#include <hip/hip_runtime.h>

// ---------------------------------------------------------------------------
// GNNQNetwork hetero-GAT, MI355X fp32. Round 13 = exact revert to R11 (504us,
// session best). R12's kernel-merge regressed (+13us): dispatch-ID spacing
// shows ~57 harness memset/restore dispatches per iteration (~180us fixed) —
// the kernel-sum vs dur_us gap is HARNESS overhead, not launch boundaries,
// so merging kernels buys nothing and the redundant vs/vd compute cost 20us.
// Edge kernels sit at the measured ~11.5cy/random-lane-request wall
// (edgeA 3 req/edge + edgeB 2-3 req/edge = ~265us floor, measured ~266).
// Structure: prep+precompute ~21us, edgeA ~130, edgeB ~137, tail ~30.
// ---------------------------------------------------------------------------

constexpr int kNT = 100000, kNRV = 200000, kNR = 300000, kE = 400000;
constexpr int kSLOT = 1088;        // per-et P tile: 16x64 acc + 64 cnt
constexpr int kPSZ  = 6 * kSLOT;   // 6528
constexpr int kNBE  = 342;         // blocks per edge type
constexpr int kNTH  = kNBE * 256;  // 87552 threads per edge type
constexpr int kEPT  = 5;           // edge slots per thread (5*87552 >= 400k)

// workspace offsets in 4-byte units (total 34.56 MB <= 34.61 proven)
constexpr long long OFF_C    = 0;        // 6*2176 C rows + bias@2048
constexpr long long OFF_VS   = 13056;    // 6*20
constexpr long long OFF_VD   = 13176;    // 6*20
constexpr long long OFF_P4   = 13296;    // 4 staged P copies: 4*6528 = 26112
constexpr long long OFF_LS6  = 39408;    // dense src logits, 1.2M
constexpr long long OFF_LD6  = 1239408;  // dense dst logits, 1.2M
constexpr long long OFF_W16  = 2439408;  // 2.4M halves = 1.2M floats
constexpr long long OFF_DEN  = 3639408;  // {den,batch} float2 x 1.2M = 2.4M
constexpr long long OFF_SRV  = 6039408;  // rv recs: 200k*8 floats (32B)
constexpr long long OFF_ST   = 7639408;  // t recs: 100k*4 floats (16B)
constexpr long long OFF_SR   = 8039408;  // r recs: 300k*2 floats (8B)
// end 8639408 floats = 34.558 MB

// per-et tables. src type: rv,t,r,rv,t,r ; dst type: t,rv,rv,r,r,t
__constant__ const int kDRB[6]  = {0, 100000, 300000, 500000, 800000, 1100000};
__constant__ const int kDLEN[6] = {100000, 200000, 200000, 300000, 300000, 100000};
__constant__ const int kLSB6[6] = {0, 400000, 600000, 200000, 500000, 900000};

// ---------------------------------------------------------------------------
__device__ __forceinline__ int lowb(const int* a, int n, int v) {
  int lo = 0, hi = n;
  while (lo < hi) { int mid = (lo + hi) >> 1; if (a[mid] < v) lo = mid + 1; else hi = mid; }
  return lo;
}

static __device__ __forceinline__ unsigned p2h(float a, float b) {
  _Float16 ha = (_Float16)a, hb = (_Float16)b;
  unsigned short ua = __builtin_bit_cast(unsigned short, ha);
  unsigned short ub = __builtin_bit_cast(unsigned short, hb);
  return (unsigned)ua | ((unsigned)ub << 16);
}

// ---------------------------------------------------------------------------
// precompute: C = enc @ W (rows 0..K-1, bias row @2048), vsw/vdw, P4 zero
__global__ __launch_bounds__(256) void precompute_kernel(
    const float* encW_t, const float* encb_t,
    const float* encW_rv, const float* encb_rv,
    const float* encW_r, const float* encb_r,
    const float* W0, const float* as0, const float* ad0,
    const float* W1, const float* as1, const float* ad1,
    const float* W2, const float* as2, const float* ad2,
    const float* W3, const float* as3, const float* ad3,
    const float* W4, const float* as4, const float* ad4,
    const float* W5, const float* as5, const float* ad5,
    float* Cws, float* vsw, float* vdw, float* P4)
{
  const float* encW[3] = {encW_t, encW_rv, encW_r};
  const float* encb[3] = {encb_t, encb_rv, encb_r};
  const int    Ks[3]   = {8, 13, 4};
  const float* Wv[6]  = {W0, W1, W2, W3, W4, W5};
  const float* asv[6] = {as0, as1, as2, as3, as4, as5};
  const float* adv[6] = {ad0, ad1, ad2, ad3, ad4, ad5};
  const int srcT[6] = {1, 0, 2, 1, 0, 2};
  const int dstT[6] = {0, 1, 1, 2, 2, 0};

  __shared__ float Cl[2176];
  __shared__ float wv[128];

  int et = blockIdx.x;
  int tid = threadIdx.x;
  int st = srcT[et], dt = dstT[et];
  const float* eW = encW[st];
  const float* eB = encb[st];
  int K = Ks[st];
  const float* W = Wv[et];
  const float* a_s = asv[et];
  const float* a_d = adv[et];
  float* Cslot = Cws + et * 2176;

  // zero P4 (grid-strided across the 6 blocks)
  for (int i = et * 256 + tid; i < 4 * kPSZ; i += 6 * 256) P4[i] = 0.f;

  for (int idx = tid; idx < (K + 1) * 128; idx += 256) {
    int r = idx >> 7, j = idx & 127;
    const float* row = (r < K) ? (eW + r * 128) : eB;
    float acc = 0.f;
    for (int m = 0; m < 128; ++m) acc += row[m] * W[m * 128 + j];
    int o = (r < K) ? (r * 128 + j) : (2048 + j);
    Cl[o] = acc;
    Cslot[o] = acc;
  }
  if (tid < 128) {
    float acc = 0.f;
    for (int j = 0; j < 128; ++j) acc += W[tid * 128 + j] * a_d[j];
    wv[tid] = acc;
  }
  __syncthreads();
  if (tid <= K) {
    const float* row = (tid < K) ? (Cl + tid * 128) : (Cl + 2048);
    float acc = 0.f;
    for (int j = 0; j < 128; ++j) acc += row[j] * a_s[j];
    vsw[et * 20 + (tid < K ? tid : 16)] = acc;
  }
  int KD = Ks[dt];
  if (tid >= 32 && tid <= 32 + KD) {
    int k = tid - 32;
    const float* row = (k < KD) ? (encW[dt] + k * 128) : encb[dt];
    float acc = 0.f;
    for (int m = 0; m < 128; ++m) acc += row[m] * wv[m];
    vdw[et * 20 + (k < KD ? k : 16)] = acc;
  }
}

// ---------------------------------------------------------------------------
// prep: per node, write x-only src recs, dense LS6/LD6 logits, DEN {0, b}.
__global__ __launch_bounds__(256) void prep_kernel(
    const float* __restrict__ x_t, const float* __restrict__ x_rv,
    const float* __restrict__ x_r,
    const int* __restrict__ bt, const int* __restrict__ brv,
    const int* __restrict__ br,
    const float* __restrict__ vsw, const float* __restrict__ vdw,
    uint4* __restrict__ SRVq, uint4* __restrict__ STq, uint2* __restrict__ SRq,
    float* __restrict__ LS6, float* __restrict__ LD6,
    float2* __restrict__ DEN)
{
  int n = blockIdx.x * 256 + threadIdx.x;
  if (n >= kNT + kNRV + kNR) return;
  if (n < kNT) {
    // tile: src roles et1,et4 (K=8); dst roles et0,et5
    const float* xr = x_t + n * 8;
    float bf = (float)bt[n];
    const float* vsA = vsw + 1 * 20, *vsB = vsw + 4 * 20;
    const float* vdA = vdw + 0 * 20, *vdB = vdw + 5 * 20;
    float x[8]; float a0 = 0, a1 = 0, a2 = 0, a3 = 0;
#pragma unroll
    for (int k = 0; k < 8; ++k) {
      x[k] = xr[k];
      a0 += x[k] * vsA[k]; a1 += x[k] * vsB[k];
      a2 += x[k] * vdA[k]; a3 += x[k] * vdB[k];
    }
    STq[n] = make_uint4(p2h(x[0], x[1]), p2h(x[2], x[3]),
                        p2h(x[4], x[5]), p2h(x[6], x[7]));
    LS6[400000 + n] = a0 + vsA[16];
    LS6[500000 + n] = a1 + vsB[16];
    LD6[n] = a2 + vdA[16];
    LD6[1100000 + n] = a3 + vdB[16];
    DEN[n] = make_float2(0.f, bf);
    DEN[1100000 + n] = make_float2(0.f, bf);
  } else if (n < kNT + kNRV) {
    int m = n - kNT;
    // rv: src roles et0,et3 (K=13); dst roles et1,et2
    const float* xr = x_rv + m * 13;
    float bf = (float)brv[m];
    const float* vsA = vsw + 0 * 20, *vsB = vsw + 3 * 20;
    const float* vdA = vdw + 1 * 20, *vdB = vdw + 2 * 20;
    float x[13]; float a0 = 0, a1 = 0, a2 = 0, a3 = 0;
#pragma unroll
    for (int k = 0; k < 13; ++k) {
      x[k] = xr[k];
      a0 += x[k] * vsA[k]; a1 += x[k] * vsB[k];
      a2 += x[k] * vdA[k]; a3 += x[k] * vdB[k];
    }
    SRVq[(long long)m * 2] =
        make_uint4(p2h(x[0], x[1]), p2h(x[2], x[3]), p2h(x[4], x[5]), p2h(x[6], x[7]));
    SRVq[(long long)m * 2 + 1] =
        make_uint4(p2h(x[8], x[9]), p2h(x[10], x[11]), p2h(x[12], 0.f), 0);
    LS6[m] = a0 + vsA[16];
    LS6[200000 + m] = a1 + vsB[16];
    LD6[100000 + m] = a2 + vdA[16];
    LD6[300000 + m] = a3 + vdB[16];
    DEN[100000 + m] = make_float2(0.f, bf);
    DEN[300000 + m] = make_float2(0.f, bf);
  } else {
    int m = n - kNT - kNRV;
    // road: src roles et2,et5 (K=4); dst roles et3,et4
    const float* xr = x_r + m * 4;
    float bf = (float)br[m];
    const float* vsA = vsw + 2 * 20, *vsB = vsw + 5 * 20;
    const float* vdA = vdw + 3 * 20, *vdB = vdw + 4 * 20;
    float x[4]; float a0 = 0, a1 = 0, a2 = 0, a3 = 0;
#pragma unroll
    for (int k = 0; k < 4; ++k) {
      x[k] = xr[k];
      a0 += x[k] * vsA[k]; a1 += x[k] * vsB[k];
      a2 += x[k] * vdA[k]; a3 += x[k] * vdB[k];
    }
    SRq[m] = make_uint2(p2h(x[0], x[1]), p2h(x[2], x[3]));
    LS6[600000 + m] = a0 + vsA[16];
    LS6[900000 + m] = a1 + vsB[16];
    LD6[500000 + m] = a2 + vdA[16];
    LD6[800000 + m] = a3 + vdB[16];
    DEN[500000 + m] = make_float2(0.f, bf);
    DEN[800000 + m] = make_float2(0.f, bf);
  }
}

// ---------------------------------------------------------------------------
__device__ __forceinline__ void pickSD(
    int et,
    const int* s0, const int* s1, const int* s2,
    const int* s3, const int* s4, const int* s5,
    const int* d0, const int* d1, const int* d2,
    const int* d3, const int* d4, const int* d5,
    const int*& sp, const int*& dp)
{
  switch (et) {
    case 0: sp = s0; dp = d0; break;
    case 1: sp = s1; dp = d1; break;
    case 2: sp = s2; dp = d2; break;
    case 3: sp = s3; dp = d3; break;
    case 4: sp = s4; dp = d4; break;
    default: sp = s5; dp = d5; break;
  }
}

// ---------------------------------------------------------------------------
// edgeA: w = exp(leaky(ls+ld)); W16[i] = w (streamed); DEN.x += w (atomic).
// Read-only gathers (LS6, LD6) fully separated from the atomic region (DEN).
__global__ __launch_bounds__(256, 8) void edgeA_kernel(
    const int* s0, const int* s1, const int* s2,
    const int* s3, const int* s4, const int* s5,
    const int* d0, const int* d1, const int* d2,
    const int* d3, const int* d4, const int* d5,
    const float* __restrict__ LS6, const float* __restrict__ LD6,
    _Float16* __restrict__ W16, float* __restrict__ DENf)
{
  int et = blockIdx.x / kNBE;
  int bIdx = blockIdx.x - et * kNBE;
  const int* sp; const int* dp;
  pickSD(et, s0, s1, s2, s3, s4, s5, d0, d1, d2, d3, d4, d5, sp, dp);
  const float* Lsrc = LS6 + kLSB6[et];
  const float* Ldst = LD6 + kDRB[et];
  const int drb = kDRB[et];
  _Float16* Wet = W16 + (long long)et * kE;
  int base = bIdx * 256 + (int)threadIdx.x;

  int s[kEPT], d[kEPT]; bool ok[kEPT];
#pragma unroll
  for (int j = 0; j < kEPT; ++j) {
    int e = base + j * kNTH;
    ok[j] = e < kE;
    int ee = ok[j] ? e : 0;
    s[j] = sp[ee]; d[j] = dp[ee];
  }
  float ls[kEPT];
#pragma unroll
  for (int j = 0; j < kEPT; ++j) ls[j] = Lsrc[s[j]];
  float ld[kEPT];
#pragma unroll
  for (int j = 0; j < kEPT; ++j) ld[j] = Ldst[d[j]];
#pragma unroll
  for (int j = 0; j < kEPT; ++j) {
    float t = ls[j] + ld[j];
    t = t > 0.f ? t : 0.2f * t;
    float w = __expf(t);
    if (ok[j]) {
      Wet[base + j * kNTH] = (_Float16)w;
      unsafeAtomicAdd(&DENf[(long long)(drb + d[j]) * 2], w);
    }
  }
}

// ---------------------------------------------------------------------------
// edgeB: streamed W16 read + DEN {den,batch} gather + x-rec gather;
// alpha*x into LDS [k][64 batches]; cnt sweep; dump to P4.
template <int TYPE>
__device__ __forceinline__ void ebflow(
    int bIdx,
    const int* __restrict__ sp, const int* __restrict__ dp,
    const uint4* __restrict__ srq4, const uint2* __restrict__ srq2,
    const _Float16* __restrict__ Wet, const float2* __restrict__ DEN2,
    int drb, int dlen, float* lp)
{
  constexpr int K = (TYPE == 0) ? 8 : ((TYPE == 1) ? 13 : 4);
  const int tid = threadIdx.x;
  const int lane = tid & 63;
  int base = bIdx * 256 + tid;

  int s[kEPT], d[kEPT]; bool ok[kEPT];
#pragma unroll
  for (int j = 0; j < kEPT; ++j) {
    int e = base + j * kNTH;
    ok[j] = e < kE;
    int ee = ok[j] ? e : 0;
    s[j] = sp[ee]; d[j] = dp[ee];
  }
  float w[kEPT];
#pragma unroll
  for (int j = 0; j < kEPT; ++j) {
    int e = base + j * kNTH;
    w[j] = (float)Wet[ok[j] ? e : 0];
  }
  uint4 q0[kEPT], q1[kEPT]; uint2 r2v[kEPT];
#pragma unroll
  for (int j = 0; j < kEPT; ++j) {
    if (TYPE == 0) {
      q0[j] = srq4[s[j]];
    } else if (TYPE == 1) {
      q0[j] = srq4[(long long)s[j] * 2];
      q1[j] = srq4[(long long)s[j] * 2 + 1];
    } else {
      r2v[j] = srq2[s[j]];
    }
  }
  float2 f2[kEPT];
#pragma unroll
  for (int j = 0; j < kEPT; ++j) f2[j] = DEN2[drb + d[j]];

#pragma unroll
  for (int j = 0; j < kEPT; ++j) {
    if (!ok[j]) continue;
    int b = (int)f2[j].y;
    float alpha = w[j] / fmaxf(f2[j].x, 1e-16f);
    float xv[K];
    if (TYPE == 0) {
      const _Float16* h = (const _Float16*)&q0[j];
#pragma unroll
      for (int k = 0; k < 8; ++k) xv[k] = (float)h[k];
    } else if (TYPE == 1) {
      const _Float16* h = (const _Float16*)&q0[j];
#pragma unroll
      for (int k = 0; k < 8; ++k) xv[k] = (float)h[k];
      const _Float16* h2 = (const _Float16*)&q1[j];
#pragma unroll
      for (int k = 0; k < 5; ++k) xv[8 + k] = (float)h2[k];
    } else {
      const _Float16* h = (const _Float16*)&r2v[j];
#pragma unroll
      for (int k = 0; k < 4; ++k) xv[k] = (float)h[k];
    }
#pragma unroll
    for (int k = 0; k < K; ++k) atomicAdd(lp + k * 64 + b, alpha * xv[k]);
  }

  // cnt: dense sweep of DEN {den,batch}; wave-segmented scan, one LDS
  // atomic per batch run (batch ids sorted by node index).
  for (int base2 = bIdx * 256 + (tid & ~63); base2 < dlen; base2 += kNTH) {
    int j2 = base2 + lane;
    bool a2 = j2 < dlen;
    float2 r2 = a2 ? DEN2[drb + j2] : make_float2(0.f, 0.f);
    int b2 = a2 ? (int)r2.y : (64 + lane);
    int v = (a2 && r2.x > 0.f) ? 1 : 0;
#pragma unroll
    for (int d2 = 1; d2 < 64; d2 <<= 1) {
      int ob = __shfl_up(b2, d2);
      int ov = __shfl_up(v, d2);
      if (lane >= d2 && ob == b2) v += ov;
    }
    int bn = __shfl_down(b2, 1);
    if (((lane == 63) || (bn != b2)) && v > 0) atomicAdd(lp + 1024 + b2, (float)v);
  }
}

__global__ __launch_bounds__(256, 4) void edgeB_kernel(
    const int* s0, const int* s1, const int* s2,
    const int* s3, const int* s4, const int* s5,
    const int* d0, const int* d1, const int* d2,
    const int* d3, const int* d4, const int* d5,
    const uint4* SRVq, const uint4* STq, const uint2* SRq,
    const _Float16* __restrict__ W16, const float2* __restrict__ DEN2,
    float* __restrict__ P4)
{
  __shared__ float lp[kSLOT];
  for (int j = threadIdx.x; j < kSLOT; j += 256) lp[j] = 0.f;
  __syncthreads();
  int et = blockIdx.x / kNBE;
  int bIdx = blockIdx.x - et * kNBE;
  const _Float16* Wet = W16 + (long long)et * kE;
  constexpr int KK[6] = {13, 8, 4, 13, 8, 4};
  switch (et) {
    case 0: ebflow<1>(bIdx, s0, d0, SRVq, nullptr, Wet, DEN2, 0,       100000, lp); break;
    case 1: ebflow<0>(bIdx, s1, d1, STq,  nullptr, Wet, DEN2, 100000,  200000, lp); break;
    case 2: ebflow<2>(bIdx, s2, d2, nullptr, SRq,  Wet, DEN2, 300000,  200000, lp); break;
    case 3: ebflow<1>(bIdx, s3, d3, SRVq, nullptr, Wet, DEN2, 500000,  300000, lp); break;
    case 4: ebflow<0>(bIdx, s4, d4, STq,  nullptr, Wet, DEN2, 800000,  300000, lp); break;
    default: ebflow<2>(bIdx, s5, d5, nullptr, SRq, Wet, DEN2, 1100000, 100000, lp); break;
  }
  __syncthreads();
  int K = KK[et];
  float* slab = P4 + (long long)(blockIdx.x & 3) * kPSZ + (long long)et * kSLOT;
  for (int i = threadIdx.x; i < kSLOT; i += 256) {
    if (i >= K * 64 && i < 1024) continue;
    float v = lp[i];
    if (v != 0.f) unsafeAtomicAdd(&slab[i], v);
  }
}

// ---------------------------------------------------------------------------
// tail: grid 64 graphs x 8 column-groups. Each block redundantly builds
// xrow for its graph, then computes 64 output columns (two half-K slices).
__global__ __launch_bounds__(128) void tail_kernel(
    const int* __restrict__ bt, const int* __restrict__ brv, const int* __restrict__ br,
    const float* __restrict__ xp,
    const float* __restrict__ fc1W, const float* __restrict__ fc1b,
    const float* __restrict__ fc2W, const float* __restrict__ fc2b,
    const float* __restrict__ outW, const float* __restrict__ outb,
    const float* __restrict__ b_rv2t, const float* __restrict__ b_r2t,
    const float* __restrict__ b_t2rv, const float* __restrict__ b_r2rv,
    const float* __restrict__ b_rv2r, const float* __restrict__ b_t2r,
    const float* __restrict__ Cws, const float* __restrict__ P4,
    float* __restrict__ out)
{
  int b = blockIdx.x >> 3;
  int half = blockIdx.x & 7;
  int tid = threadIdx.x;
  __shared__ float xrow[512];
  __shared__ float p1s[128];
  __shared__ float xps[64];
  __shared__ float psA[15], psB[15];
  __shared__ float part[128];
  __shared__ int cnts[3];

  if (tid < 64) xps[tid] = xp[b * 64 + tid];
  if (tid >= 64 && tid < 67) {
    int t = tid - 64;
    const int* ba = (t == 0) ? bt : (t == 1 ? brv : br);
    int N = (t == 0) ? kNT : (t == 1 ? kNRV : kNR);
    cnts[t] = lowb(ba, N, b + 1) - lowb(ba, N, b);
  }
  __syncthreads();

  // player branch
  float a = fc1b[tid];
  for (int k = 0; k < 64; ++k) a += xps[k] * fc1W[k * 128 + tid];
  p1s[tid] = fmaxf(a, 0.f);
  __syncthreads();
  float a2 = fc2b[tid];
  for (int k = 0; k < 128; ++k) a2 += p1s[k] * fc2W[k * 128 + tid];
  xrow[384 + tid] = fmaxf(a2, 0.f);

  const int etA[3] = {0, 1, 3}, etB[3] = {5, 2, 4};
  const int KAv[3] = {13, 8, 13}, KBv[3] = {4, 4, 8};
  for (int t3 = 0; t3 < 3; ++t3) {
    __syncthreads();
    int eA = etA[t3], eB = etB[t3];
    if (tid < 15) {
      int idx = (tid < 14) ? (tid * 64 + b) : (1024 + b);
      float sum = 0.f;
#pragma unroll
      for (int c = 0; c < 4; ++c) sum += P4[c * kPSZ + eA * kSLOT + idx];
      psA[tid] = sum;
    } else if (tid < 30) {
      int t = tid - 15;
      int idx = (t < 14) ? (t * 64 + b) : (1024 + b);
      float sum = 0.f;
#pragma unroll
      for (int c = 0; c < 4; ++c) sum += P4[c * kPSZ + eB * kSLOT + idx];
      psB[t] = sum;
    }
    __syncthreads();
    int KA = KAv[t3], KB = KBv[t3];
    const float* CA = Cws + eA * 2176;
    const float* CB = Cws + eB * 2176;
    float v = psA[14] * CA[2048 + tid] + psB[14] * CB[2048 + tid];
    for (int k = 0; k < KA; ++k) v += psA[k] * CA[k * 128 + tid];
    for (int k = 0; k < KB; ++k) v += psB[k] * CB[k * 128 + tid];
    float cnt = (float)max(cnts[t3], 1);
    const float* bb1 = (t3 == 0) ? b_rv2t : (t3 == 1 ? b_t2rv : b_rv2r);
    const float* bb2 = (t3 == 0) ? b_r2t  : (t3 == 1 ? b_r2rv : b_t2r);
    xrow[t3 * 128 + tid] = v / cnt + bb1[tid] + bb2[tid];
  }
  __syncthreads();

  // output GEMV slice: 64 columns c = half*64 + (tid&63); k-half per tid>>6
  {
    int c = half * 64 + (tid & 63);
    int kh = tid >> 6;                       // 0 or 1
    const float* Wc = outW + c;
    float acc = 0.f;
    int k0 = kh * 256;
#pragma unroll 8
    for (int k = k0; k < k0 + 256; ++k) acc += xrow[k] * Wc[(long long)k * 512];
    part[tid] = acc;
    __syncthreads();
    if (tid < 64) out[b * 512 + c] = outb[c] + part[tid] + part[tid + 64];
  }
}

// ---------------------------------------------------------------------------
extern "C" void kernel_launch(void* const* d_in, const int* in_sizes, int n_in,
                              void* d_out, int out_size, void* d_ws, size_t ws_size,
                              hipStream_t stream) {
  const float* x_tile   = (const float*)d_in[0];
  const float* x_rv     = (const float*)d_in[1];
  const float* x_road   = (const float*)d_in[2];
  const float* x_player = (const float*)d_in[3];
  const float* enc_t_W  = (const float*)d_in[4];
  const float* enc_t_b  = (const float*)d_in[5];
  const float* enc_rv_W = (const float*)d_in[6];
  const float* enc_rv_b = (const float*)d_in[7];
  const float* enc_r_W  = (const float*)d_in[8];
  const float* enc_r_b  = (const float*)d_in[9];
  const float* W[6]; const float* As[6]; const float* Ad[6]; const float* Bb[6];
  for (int et = 0; et < 6; ++et) {
    W[et]  = (const float*)d_in[10 + 4 * et];
    As[et] = (const float*)d_in[11 + 4 * et];
    Ad[et] = (const float*)d_in[12 + 4 * et];
    Bb[et] = (const float*)d_in[13 + 4 * et];
  }
  const float* fc1W = (const float*)d_in[34];
  const float* fc1b = (const float*)d_in[35];
  const float* fc2W = (const float*)d_in[36];
  const float* fc2b = (const float*)d_in[37];
  const float* outW = (const float*)d_in[38];
  const float* outb = (const float*)d_in[39];
  const int* esrc[6]; const int* edst[6];
  for (int et = 0; et < 6; ++et) {
    esrc[et] = (const int*)d_in[40 + 2 * et];
    edst[et] = (const int*)d_in[41 + 2 * et];
  }
  const int* batch_t  = (const int*)d_in[52];
  const int* batch_rv = (const int*)d_in[53];
  const int* batch_r  = (const int*)d_in[54];

  float* wsF = (float*)d_ws;
  float* Cws  = wsF + OFF_C;
  float* vsw  = wsF + OFF_VS;
  float* vdw  = wsF + OFF_VD;
  float* P4   = wsF + OFF_P4;
  float* LS6  = wsF + OFF_LS6;
  float* LD6  = wsF + OFF_LD6;
  _Float16* W16 = (_Float16*)(wsF + OFF_W16);
  float* DENf = wsF + OFF_DEN;
  float2* DEN2 = (float2*)(wsF + OFF_DEN);
  uint4* SRVq = (uint4*)(wsF + OFF_SRV);
  uint4* STq  = (uint4*)(wsF + OFF_ST);
  uint2* SRq  = (uint2*)(wsF + OFF_SR);
  float* out  = (float*)d_out;

  precompute_kernel<<<6, 256, 0, stream>>>(
      enc_t_W, enc_t_b, enc_rv_W, enc_rv_b, enc_r_W, enc_r_b,
      W[0], As[0], Ad[0], W[1], As[1], Ad[1], W[2], As[2], Ad[2],
      W[3], As[3], Ad[3], W[4], As[4], Ad[4], W[5], As[5], Ad[5],
      Cws, vsw, vdw, P4);

  prep_kernel<<<(kNT + kNRV + kNR + 255) / 256, 256, 0, stream>>>(
      x_tile, x_rv, x_road, batch_t, batch_rv, batch_r, vsw, vdw,
      SRVq, STq, SRq, LS6, LD6, DEN2);

  edgeA_kernel<<<6 * kNBE, 256, 0, stream>>>(
      esrc[0], esrc[1], esrc[2], esrc[3], esrc[4], esrc[5],
      edst[0], edst[1], edst[2], edst[3], edst[4], edst[5],
      LS6, LD6, W16, DENf);

  edgeB_kernel<<<6 * kNBE, 256, 0, stream>>>(
      esrc[0], esrc[1], esrc[2], esrc[3], esrc[4], esrc[5],
      edst[0], edst[1], edst[2], edst[3], edst[4], edst[5],
      SRVq, STq, SRq, W16, DEN2, P4);

  tail_kernel<<<64 * 8, 128, 0, stream>>>(
      batch_t, batch_rv, batch_r, x_player,
      fc1W, fc1b, fc2W, fc2b, outW, outb,
      Bb[0], Bb[5], Bb[1], Bb[2], Bb[3], Bb[4],
      Cws, P4, out);

  (void)in_sizes; (void)n_in; (void)out_size; (void)ws_size;
}